// Round 1
// baseline (341.507 us; speedup 1.0000x reference)
//
#include <hip/hip_runtime.h>

#define G 16
#define N 40000
#define D 64      // z_dim; 16 float4 per node
#define HID 256
#define C 5
#define CHUNK 400               // nodes per block (400/16 node-lanes = 25 iters)
#define NCHUNK (N / CHUNK)      // 100

// Workspace layout (bytes):
//   S   : G*C*D floats = 20480 B  @ 0        (class sums, atomically accumulated)
//   cnt : C ints                  @ 20480    (class counts)
//   M2  : G*C*D floats            @ 20736    (final per-(g,class) additive vector)

__global__ __launch_bounds__(256) void k_count(const int* __restrict__ lab,
                                               int* __restrict__ cnt) {
    __shared__ int sc[C];
    const int tid = threadIdx.x;
    if (tid < C) sc[tid] = 0;
    __syncthreads();
    for (int i = blockIdx.x * 256 + tid; i < N; i += gridDim.x * 256)
        atomicAdd(&sc[lab[i]], 1);
    __syncthreads();
    if (tid < C) atomicAdd(&cnt[tid], sc[tid]);
}

__global__ __launch_bounds__(256) void k_sums(const float4* __restrict__ x,
                                              const int* __restrict__ lab,
                                              float* __restrict__ S) {
    const int g    = blockIdx.y;
    const int base = blockIdx.x * CHUNK;
    const int tid  = threadIdx.x;
    const int q    = tid & 15;   // dim-group (4 floats)
    const int r    = tid >> 4;   // node lane 0..15

    float4 acc[C];
#pragma unroll
    for (int c = 0; c < C; ++c) acc[c] = make_float4(0.f, 0.f, 0.f, 0.f);

    const float4* xg = x + (size_t)g * N * 16;
    for (int i = r; i < CHUNK; i += 16) {
        const int n   = base + i;
        const int lbl = lab[n];
        float4 v = xg[(size_t)n * 16 + q];
#pragma unroll
        for (int c = 0; c < C; ++c) {
            const float m = (lbl == c) ? 1.f : 0.f;
            acc[c].x = fmaf(m, v.x, acc[c].x);
            acc[c].y = fmaf(m, v.y, acc[c].y);
            acc[c].z = fmaf(m, v.z, acc[c].z);
            acc[c].w = fmaf(m, v.w, acc[c].w);
        }
    }

    __shared__ float4 red[C][16][16];   // [class][r][q] = 20 KB
#pragma unroll
    for (int c = 0; c < C; ++c) red[c][r][q] = acc[c];
    __syncthreads();
    for (int s = 8; s >= 1; s >>= 1) {
        if (r < s) {
#pragma unroll
            for (int c = 0; c < C; ++c) {
                float4 a = red[c][r][q], b = red[c][r + s][q];
                a.x += b.x; a.y += b.y; a.z += b.z; a.w += b.w;
                red[c][r][q] = a;
            }
        }
        __syncthreads();
    }
    if (r == 0) {
#pragma unroll
        for (int c = 0; c < C; ++c) {
            float4 a = red[c][0][q];
            float* dst = S + ((g * C + c) * D) + q * 4;
            atomicAdd(dst + 0, a.x);
            atomicAdd(dst + 1, a.y);
            atomicAdd(dst + 2, a.z);
            atomicAdd(dst + 3, a.w);
        }
    }
}

// One block per (g, c): M2 = relu((S/cnt) @ W1 + b1) @ W2 + b2
__global__ __launch_bounds__(256) void k_mlp(const float* __restrict__ S,
                                             const int* __restrict__ cnt,
                                             const float* __restrict__ W1,
                                             const float* __restrict__ b1,
                                             const float* __restrict__ W2,
                                             const float* __restrict__ b2,
                                             float* __restrict__ M2) {
    const int gc  = blockIdx.x;   // g*C + c
    const int tid = threadIdx.x;
    __shared__ float xm[D];
    __shared__ float H[HID];
    if (tid < D) {
        int cc = cnt[gc % C];
        if (cc < 1) cc = 1;
        xm[tid] = S[gc * D + tid] / (float)cc;
    }
    __syncthreads();
    float m1 = 0.f;
#pragma unroll
    for (int d = 0; d < D; ++d) m1 = fmaf(xm[d], W1[d * HID + tid], m1);
    m1 += b1[tid];
    H[tid] = m1 > 0.f ? m1 : 0.f;
    __syncthreads();
    if (tid < D) {
        float m2 = 0.f;
        for (int f = 0; f < HID; ++f) m2 = fmaf(H[f], W2[f * D + tid], m2);
        M2[gc * D + tid] = m2 + b2[tid];
    }
}

__global__ __launch_bounds__(256) void k_out(const float4* __restrict__ x,
                                             const int* __restrict__ lab,
                                             const float4* __restrict__ M2,
                                             float4* __restrict__ out) {
    const int g    = blockIdx.y;
    const int base = blockIdx.x * CHUNK;
    const int tid  = threadIdx.x;
    const int q    = tid & 15;
    const int r    = tid >> 4;

    __shared__ float4 m2s[C][16];
    if (tid < C * 16) m2s[tid >> 4][tid & 15] = M2[(size_t)g * C * 16 + tid];
    __syncthreads();

    const size_t goff = (size_t)g * N * 16;
    for (int i = r; i < CHUNK; i += 16) {
        const int n   = base + i;
        const int lbl = lab[n];
        float4 v = x[goff + (size_t)n * 16 + q];
        float4 m = m2s[lbl][q];
        v.x += m.x; v.y += m.y; v.z += m.z; v.w += m.w;
        out[goff + (size_t)n * 16 + q] = v;
    }
}

extern "C" void kernel_launch(void* const* d_in, const int* in_sizes, int n_in,
                              void* d_out, int out_size, void* d_ws, size_t ws_size,
                              hipStream_t stream) {
    const float* x   = (const float*)d_in[0];
    const int*   lab = (const int*)d_in[1];
    const float* W1  = (const float*)d_in[2];
    const float* b1  = (const float*)d_in[3];
    const float* W2  = (const float*)d_in[4];
    const float* b2  = (const float*)d_in[5];
    float* out = (float*)d_out;

    char*  ws  = (char*)d_ws;
    float* S   = (float*)ws;              // 5120 floats
    int*   cnt = (int*)(ws + 20480);      // 5 ints
    float* M2  = (float*)(ws + 20736);    // 5120 floats

    // zero S + cnt (ws is poisoned 0xAA before every launch)
    hipMemsetAsync(d_ws, 0, 20736, stream);

    k_count<<<40, 256, 0, stream>>>(lab, cnt);

    dim3 grid(NCHUNK, G);
    k_sums<<<grid, 256, 0, stream>>>((const float4*)x, lab, S);

    k_mlp<<<G * C, 256, 0, stream>>>(S, cnt, W1, b1, W2, b2, M2);

    k_out<<<grid, 256, 0, stream>>>((const float4*)x, lab, (const float4*)M2,
                                    (float4*)out);
}

// Round 2
// 331.359 us; speedup vs baseline: 1.0306x; 1.0306x over previous
//
#include <hip/hip_runtime.h>

#define G 16
#define N 40000
#define D 64      // z_dim; 16 float4 per node
#define HID 256
#define C 5
#define CHUNK 400               // nodes per block (400/16 node-lanes = 25 iters)
#define NCHUNK (N / CHUNK)      // 100

typedef float v4f __attribute__((ext_vector_type(4)));

// Workspace layout (bytes):
//   S    : G*C*D floats = 20480 B  @ 0      (class sums, atomically accumulated)
//   cntf : 8 floats                @ 20480  (class counts, float)
//   M2   : G*C*D floats            @ 20736  (final per-(g,class) additive vector)

// Fused: per-class sums over nodes AND class counts (counts only from the
// blockIdx.y==0 slice, since labels are shared across all g).
__global__ __launch_bounds__(256) void k_sums(const v4f* __restrict__ x,
                                              const int* __restrict__ lab,
                                              float* __restrict__ S,
                                              float* __restrict__ cntf) {
    const int g    = blockIdx.y;
    const int base = blockIdx.x * CHUNK;
    const int tid  = threadIdx.x;
    const int q    = tid & 15;   // dim-group (4 floats)
    const int r    = tid >> 4;   // node lane 0..15

    v4f acc[C];
    float cacc[C];
#pragma unroll
    for (int c = 0; c < C; ++c) { acc[c] = (v4f)0.f; cacc[c] = 0.f; }

    const v4f* xg = x + (size_t)g * N * 16;
    for (int i = r; i < CHUNK; i += 16) {
        const int n   = base + i;
        const int lbl = lab[n];
        v4f v = xg[(size_t)n * 16 + q];
#pragma unroll
        for (int c = 0; c < C; ++c) {
            const float m = (lbl == c) ? 1.f : 0.f;
            acc[c] += m * v;          // 4 fma per class
            cacc[c] += m;             // used only on q==0 lanes
        }
    }

    __shared__ v4f   red[C][16][16];  // [class][r][q] = 20 KB
    __shared__ float scnt[C][16];
#pragma unroll
    for (int c = 0; c < C; ++c) {
        red[c][r][q] = acc[c];
        if (q == 0) scnt[c][r] = cacc[c];
    }
    __syncthreads();
    for (int s = 8; s >= 1; s >>= 1) {
        if (r < s) {
#pragma unroll
            for (int c = 0; c < C; ++c) {
                red[c][r][q] += red[c][r + s][q];
                if (q == 0) scnt[c][r] += scnt[c][r + s];
            }
        }
        __syncthreads();
    }
    if (r == 0) {
#pragma unroll
        for (int c = 0; c < C; ++c) {
            v4f a = red[c][0][q];
            float* dst = S + ((g * C + c) * D) + q * 4;
            atomicAdd(dst + 0, a.x);
            atomicAdd(dst + 1, a.y);
            atomicAdd(dst + 2, a.z);
            atomicAdd(dst + 3, a.w);
            if (q == 0 && g == 0) atomicAdd(&cntf[c], scnt[c][0]);
        }
    }
}

// One block per (g, c): M2 = relu((S/cnt) @ W1 + b1) @ W2 + b2
__global__ __launch_bounds__(256) void k_mlp(const float* __restrict__ S,
                                             const float* __restrict__ cntf,
                                             const float* __restrict__ W1,
                                             const float* __restrict__ b1,
                                             const float* __restrict__ W2,
                                             const float* __restrict__ b2,
                                             float* __restrict__ M2) {
    const int gc  = blockIdx.x;   // g*C + c
    const int tid = threadIdx.x;
    __shared__ float xm[D];
    __shared__ float H[HID];
    if (tid < D) {
        float cc = cntf[gc % C];
        if (cc < 1.f) cc = 1.f;
        xm[tid] = S[gc * D + tid] / cc;
    }
    __syncthreads();
    float m1 = 0.f;
#pragma unroll
    for (int d = 0; d < D; ++d) m1 = fmaf(xm[d], W1[d * HID + tid], m1);
    m1 += b1[tid];
    H[tid] = m1 > 0.f ? m1 : 0.f;
    __syncthreads();
    if (tid < D) {
        float m2 = 0.f;
        for (int f = 0; f < HID; ++f) m2 = fmaf(H[f], W2[f * D + tid], m2);
        M2[gc * D + tid] = m2 + b2[tid];
    }
}

__global__ __launch_bounds__(256) void k_out(const v4f* __restrict__ x,
                                             const int* __restrict__ lab,
                                             const v4f* __restrict__ M2,
                                             v4f* __restrict__ out) {
    const int g    = blockIdx.y;
    const int base = blockIdx.x * CHUNK;
    const int tid  = threadIdx.x;
    const int q    = tid & 15;
    const int r    = tid >> 4;

    __shared__ v4f m2s[C][16];
    if (tid < C * 16) m2s[tid >> 4][tid & 15] = M2[(size_t)g * C * 16 + tid];
    __syncthreads();

    const size_t goff = (size_t)g * N * 16;
    for (int i = r; i < CHUNK; i += 16) {
        const int n   = base + i;
        const int lbl = lab[n];
        v4f v = x[goff + (size_t)n * 16 + q];
        v += m2s[lbl][q];
        // nt store: don't let the output stream evict x from L2/L3
        __builtin_nontemporal_store(v, out + goff + (size_t)n * 16 + q);
    }
}

extern "C" void kernel_launch(void* const* d_in, const int* in_sizes, int n_in,
                              void* d_out, int out_size, void* d_ws, size_t ws_size,
                              hipStream_t stream) {
    const float* x   = (const float*)d_in[0];
    const int*   lab = (const int*)d_in[1];
    const float* W1  = (const float*)d_in[2];
    const float* b1  = (const float*)d_in[3];
    const float* W2  = (const float*)d_in[4];
    const float* b2  = (const float*)d_in[5];
    float* out = (float*)d_out;

    char*  ws   = (char*)d_ws;
    float* S    = (float*)ws;              // 5120 floats
    float* cntf = (float*)(ws + 20480);    // 8 floats
    float* M2   = (float*)(ws + 20736);    // 5120 floats

    // zero S + cntf (ws is poisoned 0xAA before every launch)
    hipMemsetAsync(d_ws, 0, 20512, stream);

    dim3 grid(NCHUNK, G);
    k_sums<<<grid, 256, 0, stream>>>((const v4f*)x, lab, S, cntf);

    k_mlp<<<G * C, 256, 0, stream>>>(S, cntf, W1, b1, W2, b2, M2);

    k_out<<<grid, 256, 0, stream>>>((const v4f*)x, lab, (const v4f*)M2,
                                    (v4f*)out);
}

// Round 3
// 329.086 us; speedup vs baseline: 1.0377x; 1.0069x over previous
//
#include <hip/hip_runtime.h>

#define G 16
#define N 40000
#define D 64      // z_dim; 16 float4 per node
#define HID 256
#define C 5

// k_sums geometry: NB blocks per g, each covers CHUNKS nodes (CHUNKS/16 iters)
#define NB 50
#define CHUNKS 800              // 50 iters per node-lane, exact

// k_out geometry
#define CHUNKO 400
#define NBO (N / CHUNKO)        // 100

typedef float v4f __attribute__((ext_vector_type(4)));

// Workspace layout (floats):
//   Spart   : [G][NB][C][D]  = 16*50*5*64 = 256000 floats @ 0      (block partial sums)
//   cntpart : [NB][C]        = 250 floats            @ 256000     (block partial counts, g==0 only)
//   M2      : [G][C][D]      = 5120 floats           @ 256256
// All fully written before read -> no zero-init, no memset dispatch.

__global__ __launch_bounds__(256) void k_sums(const v4f* __restrict__ x,
                                              const int* __restrict__ lab,
                                              v4f* __restrict__ Spart,
                                              float* __restrict__ cntpart) {
    const int g    = blockIdx.y;
    const int b    = blockIdx.x;
    const int base = b * CHUNKS;
    const int tid  = threadIdx.x;
    const int q    = tid & 15;   // dim-group (4 floats)
    const int r    = tid >> 4;   // node lane 0..15

    v4f acc[C];
    float cacc[C];
#pragma unroll
    for (int c = 0; c < C; ++c) { acc[c] = (v4f)0.f; cacc[c] = 0.f; }

    const v4f* xg = x + (size_t)g * N * 16;
#pragma unroll 2
    for (int i = r; i < CHUNKS; i += 16) {
        const int n   = base + i;
        const int lbl = lab[n];
        v4f v = xg[(size_t)n * 16 + q];
#pragma unroll
        for (int c = 0; c < C; ++c) {
            const float m = (lbl == c) ? 1.f : 0.f;
            acc[c] += m * v;
            cacc[c] += m;        // meaningful on q==0 lanes only
        }
    }

    __shared__ v4f   red[C][16][16];  // 20 KB
    __shared__ float scnt[C][16];
#pragma unroll
    for (int c = 0; c < C; ++c) {
        red[c][r][q] = acc[c];
        if (q == 0) scnt[c][r] = cacc[c];
    }
    __syncthreads();
    for (int s = 8; s >= 1; s >>= 1) {
        if (r < s) {
#pragma unroll
            for (int c = 0; c < C; ++c) {
                red[c][r][q] += red[c][r + s][q];
                if (q == 0) scnt[c][r] += scnt[c][r + s];
            }
        }
        __syncthreads();
    }
    // plain stores of this block's partials — no atomics, no init required
    if (r == 0) {
#pragma unroll
        for (int c = 0; c < C; ++c)
            Spart[(((size_t)g * NB + b) * C + c) * 16 + q] = red[c][0][q];
    }
    if (g == 0 && tid < C)
        cntpart[b * C + tid] = scnt[tid][0];
}

// One block per (g, c): reduce partials, then M2 = relu(mean @ W1 + b1) @ W2 + b2
__global__ __launch_bounds__(256) void k_mlp(const float* __restrict__ Spart,
                                             const float* __restrict__ cntpart,
                                             const float* __restrict__ W1,
                                             const float* __restrict__ b1,
                                             const float* __restrict__ W2,
                                             const float* __restrict__ b2,
                                             float* __restrict__ M2) {
    const int gc  = blockIdx.x;   // g*C + c
    const int g   = gc / C;
    const int c   = gc % C;
    const int tid = threadIdx.x;
    const int d   = tid & 63;
    const int grp = tid >> 6;     // 0..3

    __shared__ float rs[4][D];
    __shared__ float ccnt;
    __shared__ float xm[D];
    __shared__ float H[HID];

    // partial-sum reduce: 4 thread-groups stride over the NB partials
    float s = 0.f;
    for (int b = grp; b < NB; b += 4)
        s += Spart[(((size_t)g * NB + b) * C + c) * D + d];
    rs[grp][d] = s;

    if (tid == 0) ccnt = 0.f;
    __syncthreads();
    if (tid < NB) atomicAdd(&ccnt, cntpart[tid * C + c]);
    __syncthreads();

    if (tid < D) {
        float cc = ccnt;
        if (cc < 1.f) cc = 1.f;
        xm[tid] = (rs[0][tid] + rs[1][tid] + rs[2][tid] + rs[3][tid]) / cc;
    }
    __syncthreads();

    float m1 = 0.f;
#pragma unroll
    for (int dd = 0; dd < D; ++dd) m1 = fmaf(xm[dd], W1[dd * HID + tid], m1);
    m1 += b1[tid];
    H[tid] = m1 > 0.f ? m1 : 0.f;
    __syncthreads();
    if (tid < D) {
        float m2 = 0.f;
        for (int f = 0; f < HID; ++f) m2 = fmaf(H[f], W2[f * D + tid], m2);
        M2[gc * D + tid] = m2 + b2[tid];
    }
}

__global__ __launch_bounds__(256) void k_out(const v4f* __restrict__ x,
                                             const int* __restrict__ lab,
                                             const v4f* __restrict__ M2,
                                             v4f* __restrict__ out) {
    const int g    = blockIdx.y;
    const int base = blockIdx.x * CHUNKO;
    const int tid  = threadIdx.x;
    const int q    = tid & 15;
    const int r    = tid >> 4;

    __shared__ v4f m2s[C][16];
    if (tid < C * 16) m2s[tid >> 4][tid & 15] = M2[(size_t)g * C * 16 + tid];
    __syncthreads();

    const size_t goff = (size_t)g * N * 16;
#pragma unroll 2
    for (int i = r; i < CHUNKO; i += 16) {
        const int n   = base + i;
        const int lbl = lab[n];
        v4f v = x[goff + (size_t)n * 16 + q];
        v += m2s[lbl][q];
        // nt store: keep x resident in L2/L3 for this pass's reads
        __builtin_nontemporal_store(v, out + goff + (size_t)n * 16 + q);
    }
}

extern "C" void kernel_launch(void* const* d_in, const int* in_sizes, int n_in,
                              void* d_out, int out_size, void* d_ws, size_t ws_size,
                              hipStream_t stream) {
    const float* x   = (const float*)d_in[0];
    const int*   lab = (const int*)d_in[1];
    const float* W1  = (const float*)d_in[2];
    const float* b1  = (const float*)d_in[3];
    const float* W2  = (const float*)d_in[4];
    const float* b2  = (const float*)d_in[5];
    float* out = (float*)d_out;

    float* wsf     = (float*)d_ws;
    float* Spart   = wsf;             // 256000 floats
    float* cntpart = wsf + 256000;    // 250 floats
    float* M2      = wsf + 256256;    // 5120 floats

    dim3 gs(NB, G);
    k_sums<<<gs, 256, 0, stream>>>((const v4f*)x, lab, (v4f*)Spart, cntpart);

    k_mlp<<<G * C, 256, 0, stream>>>(Spart, cntpart, W1, b1, W2, b2, M2);

    dim3 go(NBO, G);
    k_out<<<go, 256, 0, stream>>>((const v4f*)x, lab, (const v4f*)M2,
                                  (v4f*)out);
}